// Round 15
// baseline (219.396 us; speedup 1.0000x reference)
//
#include <hip/hip_runtime.h>
#include <stdint.h>

#define S_LEN 2048
#define NB    4
#define DMOD  1024
#define NH    16
#define HD    64

typedef float f32x4 __attribute__((ext_vector_type(4)));
typedef float f32x16 __attribute__((ext_vector_type(16)));
typedef short bf16x8 __attribute__((ext_vector_type(8)));
typedef unsigned int u32x4 __attribute__((ext_vector_type(4)));
typedef unsigned short u16;
typedef unsigned int u32;

__device__ __forceinline__ u16 f32_to_bf16(float f) {
  union { float f; unsigned int u; } v; v.f = f;
  unsigned int r = v.u + 0x7fffu + ((v.u >> 16) & 1u);  // RNE
  return (u16)(r >> 16);
}

__device__ __forceinline__ float fast_exp2(float x) {
#if __has_builtin(__builtin_amdgcn_exp2f)
  return __builtin_amdgcn_exp2f(x);
#else
  return exp2f(x);
#endif
}

typedef __attribute__((address_space(1))) const unsigned int gu32;
typedef __attribute__((address_space(3))) unsigned int lu32;
__device__ __forceinline__ void async_copy16(const void* g, void* l) {
  __builtin_amdgcn_global_load_lds((gu32*)g, (lu32*)l, 16, 0, 0);
}

// ------------- fp32 -> bf16 conversion: 4 weights + 3 X tensors (RNE) -----
__global__ __launch_bounds__(256) void convert_all(
    const float* __restrict__ w0, const float* __restrict__ w1,
    const float* __restrict__ w2, const float* __restrict__ w3,
    const float* __restrict__ x0, const float* __restrict__ x1,
    const float* __restrict__ x2,
    u16* __restrict__ o0, u16* __restrict__ o1, u16* __restrict__ o2,
    u16* __restrict__ o3, u16* __restrict__ o4, u16* __restrict__ o5,
    u16* __restrict__ o6) {
  const float* in; u16* out; int n;
  switch (blockIdx.y) {
    case 0: in = w0; out = o0; n = 1 << 20; break;
    case 1: in = w1; out = o1; n = 1 << 20; break;
    case 2: in = w2; out = o2; n = 1 << 20; break;
    case 3: in = w3; out = o3; n = 1 << 20; break;
    case 4: in = x0; out = o4; n = 1 << 23; break;
    case 5: in = x1; out = o5; n = 1 << 23; break;
    default: in = x2; out = o6; n = 1 << 23; break;
  }
  for (int i = (blockIdx.x * 256 + threadIdx.x) * 4; i < n; i += gridDim.x * 1024) {
    float4 v = *(const float4*)(in + i);
    ushort4 o;
    o.x = f32_to_bf16(v.x); o.y = f32_to_bf16(v.y);
    o.z = f32_to_bf16(v.z); o.w = f32_to_bf16(v.w);
    *(ushort4*)(out + i) = o;
  }
}

// ---------------- fused QKV projection GEMM ----------------
// All-bf16, L2-blocked tile order (R9) + LDS double-buffer (R8's proven
// vmcnt(0)+syncthreads pattern). Next tile's 4 global_load_lds fly under the
// current tile's ds_read+MFMA; end-of-iter vmcnt(0) then waits only the
// residual latency. All staging is intrinsic-only -> deterministic order.
// which: 0=Q (scaled) 1=K (attn-swizzled) 2=V (transposed+swizzled).
__global__ __launch_bounds__(256) void gemm_proj(
    const u16* __restrict__ Xqb, const u16* __restrict__ Xkb, const u16* __restrict__ Xvb,
    const u16* __restrict__ Wqb, const u16* __restrict__ Wkb, const u16* __restrict__ Wvb,
    const float* __restrict__ bq, const float* __restrict__ bk, const float* __restrict__ bv,
    u16* __restrict__ Qo, u16* __restrict__ Ko, u16* __restrict__ Vo, float qscale) {
  __shared__ u16 a_lds[2][128 * 32];
  __shared__ u16 b_lds[2][128 * 32];
  const int lin = blockIdx.x + (blockIdx.y << 6) + (blockIdx.z << 9);
  const int c   = lin & 7;          // XCD
  const int idx = lin >> 3;         // 0..191 within XCD
  const int which = idx >> 6;       // 0..2
  const int t   = idx & 63;
  const int m0 = (c * 8 + (t >> 3)) * 128;
  const int n0 = (t & 7) * 128;     // n inner: A-tile reused x8 from L2

  const u16* A  = (which == 0) ? Xqb : (which == 1) ? Xkb : Xvb;
  const u16* Bw = (which == 0) ? Wqb : (which == 1) ? Wkb : Wvb;
  const float* bias = (which == 0) ? bq : (which == 1) ? bk : bv;

  const int tid  = threadIdx.x;
  const int wid  = tid >> 6;
  const int lane = tid & 63;
  const int wm = wid >> 1, wn = wid & 1;

  f32x4 acc[4][4] = {};

  // per-lane staging sources (XOR-swizzled chunk within each 32-elem row)
  const int srow0 = wid * 32 + (lane >> 2);
  const int srow1 = srow0 + 16;
  const int sc0 = (lane & 3) ^ ((srow0 >> 1) & 3);
  const int sc1 = (lane & 3) ^ ((srow1 >> 1) & 3);
  const u16* Bp0 = Bw + (size_t)(n0 + srow0) * 1024 + sc0 * 8;
  const u16* Bp1 = Bw + (size_t)(n0 + srow1) * 1024 + sc1 * 8;
  const u16* Ap0 = A + (size_t)(m0 + srow0) * 1024 + sc0 * 8;
  const u16* Ap1 = A + (size_t)(m0 + srow1) * 1024 + sc1 * 8;

  #define STAGE_PROJ(buf, kt)                                       \
    do {                                                            \
      const int k0_ = (kt) * 32;                                    \
      async_copy16(Bp0 + k0_, b_lds[buf] + wid * 1024);             \
      async_copy16(Bp1 + k0_, b_lds[buf] + wid * 1024 + 512);       \
      async_copy16(Ap0 + k0_, a_lds[buf] + wid * 1024);             \
      async_copy16(Ap1 + k0_, a_lds[buf] + wid * 1024 + 512);       \
    } while (0)

  STAGE_PROJ(0, 0);
  asm volatile("s_waitcnt vmcnt(0)" ::: "memory");
  __syncthreads();

  for (int kt = 0; kt < 32; ++kt) {
    const int cur = kt & 1;
    if (kt + 1 < 32) STAGE_PROJ(cur ^ 1, kt + 1);   // fly under compute

    bf16x8 af[4], bfr[4];
    #pragma unroll
    for (int mi = 0; mi < 4; ++mi) {
      int row = wm * 64 + mi * 16 + (lane & 15);
      int ch  = (lane >> 4) ^ ((row >> 1) & 3);
      af[mi] = *(const bf16x8*)(a_lds[cur] + row * 32 + ch * 8);
    }
    #pragma unroll
    for (int ni = 0; ni < 4; ++ni) {
      int row = wn * 64 + ni * 16 + (lane & 15);
      int ch  = (lane >> 4) ^ ((row >> 1) & 3);
      bfr[ni] = *(const bf16x8*)(b_lds[cur] + row * 32 + ch * 8);
    }
    #pragma unroll
    for (int mi = 0; mi < 4; ++mi)
      #pragma unroll
      for (int ni = 0; ni < 4; ++ni)
        acc[mi][ni] = __builtin_amdgcn_mfma_f32_16x16x32_bf16(af[mi], bfr[ni], acc[mi][ni], 0, 0, 0);

    asm volatile("s_waitcnt vmcnt(0)" ::: "memory");  // next tile landed
    __syncthreads();
  }
  #undef STAGE_PROJ

  // epilogue: C row = sbase + r (4 consecutive m = same s, b = r), col = n
  #pragma unroll
  for (int ni = 0; ni < 4; ++ni) {
    int n = n0 + wn * 64 + ni * 16 + (lane & 15);
    float bv = bias[n];
    int hh = n >> 6, dk = n & 63;
    #pragma unroll
    for (int mi = 0; mi < 4; ++mi) {
      int sbase = m0 + wm * 64 + mi * 16 + ((lane >> 4) << 2);
      int s = sbase >> 2;   // sbase % 4 == 0
      if (which == 0) {
        #pragma unroll
        for (int r = 0; r < 4; ++r)
          Qo[((size_t)(r * NH + hh) * S_LEN + s) * HD + dk] =
              f32_to_bf16((acc[mi][ni][r] + bv) * qscale);
      } else if (which == 1) {
        int dkp = (((dk >> 2) ^ (s & 15)) << 2) | (dk & 3);
        #pragma unroll
        for (int r = 0; r < 4; ++r)
          Ko[((size_t)(r * NH + hh) * S_LEN + s) * HD + dkp] =
              f32_to_bf16(acc[mi][ni][r] + bv);
      } else {
        int sp = (s & ~63) | ((((s >> 2) & 15) ^ (dk & 15)) << 2) | (s & 3);
        #pragma unroll
        for (int r = 0; r < 4; ++r)
          Vo[((size_t)(r * NH + hh) * HD + dk) * S_LEN + sp] =
              f32_to_bf16(acc[mi][ni][r] + bv);
      }
    }
  }
}

// ---------------- output projection GEMM (L2-blocked, BK=64, fp32 out) ----
__global__ __launch_bounds__(256) void gemm_out(const u16* __restrict__ Ab,
                                                const u16* __restrict__ Bw,
                                                const float* __restrict__ bias,
                                                float* __restrict__ outp) {
  __shared__ u16 a_lds[128 * 64];
  __shared__ u16 b_lds[128 * 64];
  const int lin = blockIdx.x + (blockIdx.y << 6);
  const int c   = lin & 7;
  const int idx = lin >> 3;         // 0..63
  const int m0 = (c * 8 + (idx >> 3)) * 128;
  const int n0 = (idx & 7) * 128;   // n inner: A-tile reused x8 from L2
  const int tid  = threadIdx.x;
  const int wid  = tid >> 6;
  const int lane = tid & 63;
  const int wm = wid >> 1, wn = wid & 1;

  f32x4 acc[4][4] = {};

  for (int kt = 0; kt < 16; ++kt) {
    const int k0 = kt * 64;
    __syncthreads();
    #pragma unroll
    for (int j = 0; j < 4; ++j) {
      int row = wid * 32 + j * 8 + (lane >> 3);
      int sc  = (lane & 7) ^ (row & 7);
      async_copy16(Bw + (size_t)(n0 + row) * 1024 + k0 + sc * 8,
                   b_lds + (wid * 32 + j * 8) * 64);
      async_copy16(Ab + (size_t)(m0 + row) * 1024 + k0 + sc * 8,
                   a_lds + (wid * 32 + j * 8) * 64);
    }
    asm volatile("s_waitcnt vmcnt(0)" ::: "memory");
    __syncthreads();

    #pragma unroll
    for (int s32 = 0; s32 < 2; ++s32) {
      bf16x8 af[4], bfr[4];
      #pragma unroll
      for (int mi = 0; mi < 4; ++mi) {
        int row = wm * 64 + mi * 16 + (lane & 15);
        int ch  = (s32 * 4 + (lane >> 4)) ^ (row & 7);
        af[mi] = *(const bf16x8*)(a_lds + row * 64 + ch * 8);
      }
      #pragma unroll
      for (int ni = 0; ni < 4; ++ni) {
        int row = wn * 64 + ni * 16 + (lane & 15);
        int ch  = (s32 * 4 + (lane >> 4)) ^ (row & 7);
        bfr[ni] = *(const bf16x8*)(b_lds + row * 64 + ch * 8);
      }
      #pragma unroll
      for (int mi = 0; mi < 4; ++mi)
        #pragma unroll
        for (int ni = 0; ni < 4; ++ni)
          acc[mi][ni] = __builtin_amdgcn_mfma_f32_16x16x32_bf16(af[mi], bfr[ni], acc[mi][ni], 0, 0, 0);
    }
  }

  // A rows are b*2048+s ; out is [s][b][d]
  #pragma unroll
  for (int ni = 0; ni < 4; ++ni) {
    int n = n0 + wn * 64 + ni * 16 + (lane & 15);
    float bv = bias[n];
    #pragma unroll
    for (int mi = 0; mi < 4; ++mi) {
      int sbase = m0 + wm * 64 + mi * 16 + ((lane >> 4) << 2);
      #pragma unroll
      for (int r = 0; r < 4; ++r) {
        int m = sbase + r;
        int bb = m >> 11, s = m & 2047;
        outp[((size_t)(s * NB + bb)) * 1024 + n] = acc[mi][ni][r] + bv;
      }
    }
  }
}

// ---------------- flash attention, 8-wave 32x32 swapped-QK ----------------
// Qb: [bh][s][dk] bf16 (pre-scaled). Kb: row-swizzled. Vt: [bh][dk][s'] swizzled.
// STATIC-STABILITY SOFTMAX: P = exp2(s) directly; l = exact fp32 row sum.
__global__ __launch_bounds__(512, 4) void attn_kernel(const u16* __restrict__ Qb,
                                                      const u16* __restrict__ Kb,
                                                      const u16* __restrict__ Vt,
                                                      u16* __restrict__ Oatt) {
  __shared__ u16 kbuf[2][64 * 64];
  __shared__ u16 vbuf[2][64 * 64];
  __shared__ float alds[8][32];
  const int tid = threadIdx.x;
  const int w = tid >> 6, lane = tid & 63;
  const int hi = lane >> 5, l31 = lane & 31;
  const int lin = blockIdx.x;
  const int bh = (lin & 7) + 8 * (lin >> 6);   // XCD = bh & 7
  const int qt = (lin >> 3) & 7;
  const int h = bh & 15, b = bh >> 4;
  const int q0 = qt * 256 + w * 32;
  const int key = l31 & 15;

  bf16x8 qf[4];
  {
    const u16* qp = Qb + ((size_t)bh * S_LEN + q0 + l31) * HD + hi * 8;
    #pragma unroll
    for (int s = 0; s < 4; ++s) qf[s] = *(const bf16x8*)(qp + s * 16);
  }

  f32x16 acc0 = {}, acc1 = {};
  float l_run = 0.0f;

  const int rl = w * 8 + (lane >> 3);
  const u16* ksrc = Kb + ((size_t)bh * S_LEN + rl) * HD + (lane & 7) * 8;
  const u16* vsrc = Vt + ((size_t)bh * HD + rl) * S_LEN + (lane & 7) * 8;

  async_copy16(ksrc, &kbuf[0][w * 512]);
  async_copy16(vsrc, &vbuf[0][w * 512]);
  asm volatile("s_waitcnt vmcnt(0)" ::: "memory");
  __syncthreads();

  for (int kb = 0; kb < 32; ++kb) {
    const int cur = kb & 1;
    if (kb + 1 < 32) {
      async_copy16(ksrc + (size_t)(kb + 1) * 64 * HD, &kbuf[cur ^ 1][w * 512]);
      async_copy16(vsrc + (kb + 1) * 64, &vbuf[cur ^ 1][w * 512]);
    }
    const u16* KL = kbuf[cur];
    const u16* VL = vbuf[cur];

    // ---- QK^T (swapped): D[k][q], col q = lane&31; conflict-free b64 pairs
    f32x16 pk0 = {}, pk1 = {};
    __builtin_amdgcn_s_setprio(1);
    #pragma unroll
    for (int s = 0; s < 4; ++s) {
      const int c0 = 4 * s + 2 * hi;
      const int p0 = (c0 ^ key) * 4;
      const int p1 = ((c0 + 1) ^ key) * 4;
      uint2 a0 = *(const uint2*)(KL + l31 * 64 + p0);
      uint2 a1 = *(const uint2*)(KL + l31 * 64 + p1);
      uint2 b0 = *(const uint2*)(KL + (32 + l31) * 64 + p0);
      uint2 b1 = *(const uint2*)(KL + (32 + l31) * 64 + p1);
      u32x4 kw0 = {a0.x, a0.y, a1.x, a1.y};
      u32x4 kw1 = {b0.x, b0.y, b1.x, b1.y};
      pk0 = __builtin_amdgcn_mfma_f32_32x32x16_bf16(__builtin_bit_cast(bf16x8, kw0), qf[s], pk0, 0, 0, 0);
      pk1 = __builtin_amdgcn_mfma_f32_32x32x16_bf16(__builtin_bit_cast(bf16x8, kw1), qf[s], pk1, 0, 0, 0);
    }
    __builtin_amdgcn_s_setprio(0);

    // ---- softmax numerator: P = exp2(s) directly (statically stable)
    #pragma unroll
    for (int r = 0; r < 16; ++r) {
      pk0[r] = fast_exp2(pk0[r]);
      pk1[r] = fast_exp2(pk1[r]);
    }

    // ---- row-sum (q-domain scalar l), pairwise tree
    {
      float t16[16];
      #pragma unroll
      for (int r = 0; r < 16; ++r) t16[r] = pk0[r] + pk1[r];
      float t8[8];
      #pragma unroll
      for (int r = 0; r < 8; ++r) t8[r] = t16[r] + t16[r + 8];
      float t4[4];
      #pragma unroll
      for (int r = 0; r < 4; ++r) t4[r] = t8[r] + t8[r + 4];
      float rs = (t4[0] + t4[1]) + (t4[2] + t4[3]);
#if __has_builtin(__builtin_amdgcn_permlane32_swap)
      u32 ru = __builtin_bit_cast(u32, rs);
      auto sw = __builtin_amdgcn_permlane32_swap(ru, ru, false, false);
      rs += __builtin_bit_cast(float, hi ? sw[0] : sw[1]);
#else
      rs += __shfl_xor(rs, 32);
#endif
      l_run += rs;
    }

    // ---- P -> bf16 (cvt_pk) then per-half A-frag build + PV MFMA
    u32 c0v[8], c1v[8];
    #pragma unroll
    for (int i = 0; i < 8; ++i) {
      float a0 = pk0[2 * i], b0 = pk0[2 * i + 1];
      float a1 = pk1[2 * i], b1 = pk1[2 * i + 1];
      asm("v_cvt_pk_bf16_f32 %0, %1, %2" : "=v"(c0v[i]) : "v"(a0), "v"(b0));
      asm("v_cvt_pk_bf16_f32 %0, %1, %2" : "=v"(c1v[i]) : "v"(a1), "v"(b1));
    }

    __builtin_amdgcn_s_setprio(1);
    #pragma unroll
    for (int g = 0; g < 2; ++g) {
      u32 pa0[4], pa1[4];
#if __has_builtin(__builtin_amdgcn_permlane32_swap)
      {
        auto s0 = __builtin_amdgcn_permlane32_swap(c0v[4*g+0], c0v[4*g+2], false, false);
        auto s1 = __builtin_amdgcn_permlane32_swap(c0v[4*g+1], c0v[4*g+3], false, false);
        pa0[0] = s0[0]; pa0[2] = s0[1]; pa0[1] = s1[0]; pa0[3] = s1[1];
        auto t0 = __builtin_amdgcn_permlane32_swap(c1v[4*g+0], c1v[4*g+2], false, false);
        auto t1 = __builtin_amdgcn_permlane32_swap(c1v[4*g+1], c1v[4*g+3], false, false);
        pa1[0] = t0[0]; pa1[2] = t0[1]; pa1[1] = t1[0]; pa1[3] = t1[1];
      }
#else
      {
        u32 x0 = c0v[4*g+0], x1 = c0v[4*g+1], y0 = c0v[4*g+2], y1 = c0v[4*g+3];
        u32 X0 = __shfl_xor((int)x0, 32), X1 = __shfl_xor((int)x1, 32);
        u32 Y0 = __shfl_xor((int)y0, 32), Y1 = __shfl_xor((int)y1, 32);
        pa0[0] = hi ? Y0 : x0; pa0[1] = hi ? Y1 : x1;
        pa0[2] = hi ? y0 : X0; pa0[3] = hi ? y1 : X1;
        x0 = c1v[4*g+0]; x1 = c1v[4*g+1]; y0 = c1v[4*g+2]; y1 = c1v[4*g+3];
        X0 = __shfl_xor((int)x0, 32); X1 = __shfl_xor((int)x1, 32);
        Y0 = __shfl_xor((int)y0, 32); Y1 = __shfl_xor((int)y1, 32);
        pa1[0] = hi ? Y0 : x0; pa1[1] = hi ? Y1 : x1;
        pa1[2] = hi ? y0 : X0; pa1[3] = hi ? y1 : X1;
      }
#endif
      #pragma unroll
      for (int t = 0; t < 2; ++t) {
        const int ks = t == 0 ? g : 2 + g;
        u32x4 pw = t == 0 ? (u32x4){pa0[0], pa0[1], pa0[2], pa0[3]}
                          : (u32x4){pa1[0], pa1[1], pa1[2], pa1[3]};
        bf16x8 paf = __builtin_bit_cast(bf16x8, pw);
        const int c0c = 4 * ks + 2 * hi;
        const int p0 = (c0c ^ key) * 4;
        const int p1 = ((c0c + 1) ^ key) * 4;
        uint2 va0 = *(const uint2*)(VL + l31 * 64 + p0);
        uint2 va1 = *(const uint2*)(VL + l31 * 64 + p1);
        uint2 vb0 = *(const uint2*)(VL + (32 + l31) * 64 + p0);
        uint2 vb1 = *(const uint2*)(VL + (32 + l31) * 64 + p1);
        u32x4 vw0 = {va0.x, va0.y, va1.x, va1.y};
        u32x4 vw1 = {vb0.x, vb0.y, vb1.x, vb1.y};
        acc0 = __builtin_amdgcn_mfma_f32_32x32x16_bf16(paf, __builtin_bit_cast(bf16x8, vw0), acc0, 0, 0, 0);
        acc1 = __builtin_amdgcn_mfma_f32_32x32x16_bf16(paf, __builtin_bit_cast(bf16x8, vw1), acc1, 0, 0, 0);
      }
    }
    __builtin_amdgcn_s_setprio(0);

    asm volatile("s_waitcnt vmcnt(0)" ::: "memory");
    __syncthreads();
  }

  // ---- epilogue: broadcast l to C-row domain, O = acc / l
  if (lane < 32) alds[w][l31] = l_run;
  #pragma unroll
  for (int r = 0; r < 16; ++r) {
    const int crow = (r & 3) + 8 * (r >> 2) + 4 * hi;
    const int q = q0 + crow;
    u16* op = Oatt + ((size_t)b * S_LEN + q) * DMOD + h * HD;
    const float inv = 1.0f / alds[w][crow];
    op[l31]      = f32_to_bf16(acc0[r] * inv);
    op[32 + l31] = f32_to_bf16(acc1[r] * inv);
  }
}

// ---------------- launch ----------------
extern "C" void kernel_launch(void* const* d_in, const int* in_sizes, int n_in,
                              void* d_out, int out_size, void* d_ws, size_t ws_size,
                              hipStream_t stream) {
  const float* Xq = (const float*)d_in[0];
  const float* Xk = (const float*)d_in[1];
  const float* Xv = (const float*)d_in[2];
  const float* Wq = (const float*)d_in[3];
  const float* bq = (const float*)d_in[4];
  const float* Wk = (const float*)d_in[5];
  const float* bk = (const float*)d_in[6];
  const float* Wv = (const float*)d_in[7];
  const float* bv = (const float*)d_in[8];
  const float* Wo = (const float*)d_in[9];
  const float* bo = (const float*)d_in[10];

  u16* Wqb = (u16*)d_ws;
  u16* Wkb = Wqb + (1 << 20);
  u16* Wvb = Wkb + (1 << 20);
  u16* Wob = Wvb + (1 << 20);
  u16* Qb  = Wob + (1 << 20);
  const size_t QKV = (size_t)64 * S_LEN * HD;  // 8388608 elems
  u16* Kb  = Qb + QKV;
  u16* Vt  = Kb + QKV;
  u16* Oat = Vt + QKV;
  u16* Xqb = Oat + QKV;
  u16* Xkb = Xqb + QKV;
  u16* Xvb = Xkb + QKV;

  convert_all<<<dim3(2048, 7), 256, 0, stream>>>(Wq, Wk, Wv, Wo, Xq, Xk, Xv,
                                                 Wqb, Wkb, Wvb, Wob, Xqb, Xkb, Xvb);

  // Q pre-scaled by (1/sqrt(64)) * log2(e) so softmax runs in exp2 domain
  gemm_proj<<<dim3(64, 8, 3), 256, 0, stream>>>(Xqb, Xkb, Xvb, Wqb, Wkb, Wvb,
                                                bq, bk, bv, Qb, Kb, Vt,
                                                0.125f * 1.4426950408889634f);

  attn_kernel<<<dim3(512), 512, 0, stream>>>(Qb, Kb, Vt, Oat);

  gemm_out<<<dim3(64, 8), 256, 0, stream>>>(Oat, Wob, bo, (float*)d_out);
}

// Round 16
// 207.981 us; speedup vs baseline: 1.0549x; 1.0549x over previous
//
#include <hip/hip_runtime.h>
#include <stdint.h>

#define S_LEN 2048
#define NB    4
#define DMOD  1024
#define NH    16
#define HD    64

typedef float f32x4 __attribute__((ext_vector_type(4)));
typedef float f32x16 __attribute__((ext_vector_type(16)));
typedef short bf16x8 __attribute__((ext_vector_type(8)));
typedef unsigned int u32x4 __attribute__((ext_vector_type(4)));
typedef unsigned short u16;
typedef unsigned int u32;

__device__ __forceinline__ u16 f32_to_bf16(float f) {
  union { float f; unsigned int u; } v; v.f = f;
  unsigned int r = v.u + 0x7fffu + ((v.u >> 16) & 1u);  // RNE
  return (u16)(r >> 16);
}

__device__ __forceinline__ float fast_exp2(float x) {
#if __has_builtin(__builtin_amdgcn_exp2f)
  return __builtin_amdgcn_exp2f(x);
#else
  return exp2f(x);
#endif
}

typedef __attribute__((address_space(1))) const unsigned int gu32;
typedef __attribute__((address_space(3))) unsigned int lu32;
__device__ __forceinline__ void async_copy16(const void* g, void* l) {
  __builtin_amdgcn_global_load_lds((gu32*)g, (lu32*)l, 16, 0, 0);
}

// ------------- fp32 -> bf16 weight conversion (weights only, 24 MB) -------
__global__ __launch_bounds__(256) void convert4_kernel(
    const float* __restrict__ w0, const float* __restrict__ w1,
    const float* __restrict__ w2, const float* __restrict__ w3,
    u16* __restrict__ o0, u16* __restrict__ o1,
    u16* __restrict__ o2, u16* __restrict__ o3) {
  const float* in; u16* out;
  switch (blockIdx.y) {
    case 0: in = w0; out = o0; break;
    case 1: in = w1; out = o1; break;
    case 2: in = w2; out = o2; break;
    default: in = w3; out = o3; break;
  }
  int i = (blockIdx.x * 256 + threadIdx.x) * 4;
  float4 v = *(const float4*)(in + i);
  ushort4 o;
  o.x = f32_to_bf16(v.x); o.y = f32_to_bf16(v.y);
  o.z = f32_to_bf16(v.z); o.w = f32_to_bf16(v.w);
  *(ushort4*)(out + i) = o;
}

// ---------------- fused QKV projection GEMM ----------------
// A = X fp32 DIRECT (saves the 144 MB convert pass): per K-step, reg-load
// fp32 -> RNE f32_to_bf16 -> ds_write — the R4-proven staging with FULL
// vmcnt(0) drain before the barrier (no counted vmcnt, no ordering
// assumptions -> race-free). B = W bf16 via global_load_lds.
// L2-block: XCD c owns chunks of 4 m-tiles x 8 n-panels (n inner) so the
// fp32 A-chunk (2MB) + W panel (2MB) stay L2-resident.
// which: 0=Q (scaled) 1=K (attn-swizzled) 2=V (transposed+swizzled).
__global__ __launch_bounds__(256) void gemm_proj(
    const float* __restrict__ Xq, const float* __restrict__ Xk, const float* __restrict__ Xv,
    const u16* __restrict__ Wqb, const u16* __restrict__ Wkb, const u16* __restrict__ Wvb,
    const float* __restrict__ bq, const float* __restrict__ bk, const float* __restrict__ bv,
    u16* __restrict__ Qo, u16* __restrict__ Ko, u16* __restrict__ Vo, float qscale) {
  __shared__ u16 a_lds[128 * 32];
  __shared__ u16 b_lds[128 * 32];
  const int lin = blockIdx.x + (blockIdx.y << 6) + (blockIdx.z << 9);
  const int c    = lin & 7;          // XCD
  const int idx  = lin >> 3;         // 0..191
  const int which = idx >> 6;        // 0..2
  const int r6   = idx & 63;
  const int half = r6 >> 5;
  const int w32  = r6 & 31;
  const int m0 = (((half << 3) + c) * 4 + (w32 >> 3)) * 128;
  const int n0 = (w32 & 7) * 128;    // n inner: A-chunk reused x8 from L2

  const float* A  = (which == 0) ? Xq : (which == 1) ? Xk : Xv;
  const u16* Bw   = (which == 0) ? Wqb : (which == 1) ? Wkb : Wvb;
  const float* bias = (which == 0) ? bq : (which == 1) ? bk : bv;

  const int tid  = threadIdx.x;
  const int wid  = tid >> 6;
  const int lane = tid & 63;
  const int wm = wid >> 1, wn = wid & 1;

  // A reg-staging: thread -> (row = tid>>1, k-half = tid&1), 16 fp32 = 64B
  const int arow  = tid >> 1, ahalf = tid & 1;
  const float* Ap = A + (size_t)(m0 + arow) * 1024 + ahalf * 16;
  const int akey  = (arow >> 1) & 3;
  const int slot0 = (ahalf * 2 + 0) ^ akey;
  const int slot1 = (ahalf * 2 + 1) ^ akey;
  u16* awr = a_lds + arow * 32;

  // B staging sources (XOR-swizzled 8-elem chunk, proven R9/R12 pattern)
  const int srow0 = wid * 32 + (lane >> 2);
  const int srow1 = srow0 + 16;
  const int sc0 = (lane & 3) ^ ((srow0 >> 1) & 3);
  const int sc1 = (lane & 3) ^ ((srow1 >> 1) & 3);
  const u16* Bp0 = Bw + (size_t)(n0 + srow0) * 1024 + sc0 * 8;
  const u16* Bp1 = Bw + (size_t)(n0 + srow1) * 1024 + sc1 * 8;

  f32x4 acc[4][4] = {};

  for (int kt = 0; kt < 32; ++kt) {
    const int k0 = kt * 32;
    __syncthreads();                       // prev compute's ds_reads retired

    // ---- stage B(kt) via global_load_lds
    async_copy16(Bp0 + k0, b_lds + wid * 1024);
    async_copy16(Bp1 + k0, b_lds + wid * 1024 + 512);

    // ---- A(kt): fp32 load -> RNE cvt -> ds_write (compiler waits A-loads)
    {
      float4 av0 = *(const float4*)(Ap + k0 + 0);
      float4 av1 = *(const float4*)(Ap + k0 + 4);
      float4 av2 = *(const float4*)(Ap + k0 + 8);
      float4 av3 = *(const float4*)(Ap + k0 + 12);
      u16 tmp[16];
      tmp[0]  = f32_to_bf16(av0.x); tmp[1]  = f32_to_bf16(av0.y);
      tmp[2]  = f32_to_bf16(av0.z); tmp[3]  = f32_to_bf16(av0.w);
      tmp[4]  = f32_to_bf16(av1.x); tmp[5]  = f32_to_bf16(av1.y);
      tmp[6]  = f32_to_bf16(av1.z); tmp[7]  = f32_to_bf16(av1.w);
      tmp[8]  = f32_to_bf16(av2.x); tmp[9]  = f32_to_bf16(av2.y);
      tmp[10] = f32_to_bf16(av2.z); tmp[11] = f32_to_bf16(av2.w);
      tmp[12] = f32_to_bf16(av3.x); tmp[13] = f32_to_bf16(av3.y);
      tmp[14] = f32_to_bf16(av3.z); tmp[15] = f32_to_bf16(av3.w);
      *(int4*)(awr + slot0 * 8) = *(const int4*)(tmp + 0);
      *(int4*)(awr + slot1 * 8) = *(const int4*)(tmp + 8);
    }

    // ---- FULL drain (B's global_load_lds + any stragglers), then barrier
    asm volatile("s_waitcnt vmcnt(0)" ::: "memory");
    __syncthreads();                       // also waits lgkmcnt (ds_writes)

    // ---- compute
    bf16x8 af[4], bfr[4];
    #pragma unroll
    for (int mi = 0; mi < 4; ++mi) {
      int row = wm * 64 + mi * 16 + (lane & 15);
      int ch  = (lane >> 4) ^ ((row >> 1) & 3);
      af[mi] = *(const bf16x8*)(a_lds + row * 32 + ch * 8);
    }
    #pragma unroll
    for (int ni = 0; ni < 4; ++ni) {
      int row = wn * 64 + ni * 16 + (lane & 15);
      int ch  = (lane >> 4) ^ ((row >> 1) & 3);
      bfr[ni] = *(const bf16x8*)(b_lds + row * 32 + ch * 8);
    }
    #pragma unroll
    for (int mi = 0; mi < 4; ++mi)
      #pragma unroll
      for (int ni = 0; ni < 4; ++ni)
        acc[mi][ni] = __builtin_amdgcn_mfma_f32_16x16x32_bf16(af[mi], bfr[ni], acc[mi][ni], 0, 0, 0);
  }

  // epilogue: C row = sbase + r (4 consecutive m = same s, b = r), col = n
  #pragma unroll
  for (int ni = 0; ni < 4; ++ni) {
    int n = n0 + wn * 64 + ni * 16 + (lane & 15);
    float bv = bias[n];
    int hh = n >> 6, dk = n & 63;
    #pragma unroll
    for (int mi = 0; mi < 4; ++mi) {
      int sbase = m0 + wm * 64 + mi * 16 + ((lane >> 4) << 2);
      int s = sbase >> 2;   // sbase % 4 == 0
      if (which == 0) {
        #pragma unroll
        for (int r = 0; r < 4; ++r)
          Qo[((size_t)(r * NH + hh) * S_LEN + s) * HD + dk] =
              f32_to_bf16((acc[mi][ni][r] + bv) * qscale);
      } else if (which == 1) {
        int dkp = (((dk >> 2) ^ (s & 15)) << 2) | (dk & 3);
        #pragma unroll
        for (int r = 0; r < 4; ++r)
          Ko[((size_t)(r * NH + hh) * S_LEN + s) * HD + dkp] =
              f32_to_bf16(acc[mi][ni][r] + bv);
      } else {
        int sp = (s & ~63) | ((((s >> 2) & 15) ^ (dk & 15)) << 2) | (s & 3);
        #pragma unroll
        for (int r = 0; r < 4; ++r)
          Vo[((size_t)(r * NH + hh) * HD + dk) * S_LEN + sp] =
              f32_to_bf16(acc[mi][ni][r] + bv);
      }
    }
  }
}

// ---------------- output projection GEMM (L2-blocked, BK=64, fp32 out) ----
__global__ __launch_bounds__(256) void gemm_out(const u16* __restrict__ Ab,
                                                const u16* __restrict__ Bw,
                                                const float* __restrict__ bias,
                                                float* __restrict__ outp) {
  __shared__ u16 a_lds[128 * 64];
  __shared__ u16 b_lds[128 * 64];
  const int lin = blockIdx.x + (blockIdx.y << 6);
  const int c   = lin & 7;
  const int idx = lin >> 3;         // 0..63
  const int m0 = (c * 8 + (idx >> 3)) * 128;
  const int n0 = (idx & 7) * 128;   // n inner: A-tile reused x8 from L2
  const int tid  = threadIdx.x;
  const int wid  = tid >> 6;
  const int lane = tid & 63;
  const int wm = wid >> 1, wn = wid & 1;

  f32x4 acc[4][4] = {};

  for (int kt = 0; kt < 16; ++kt) {
    const int k0 = kt * 64;
    __syncthreads();
    #pragma unroll
    for (int j = 0; j < 4; ++j) {
      int row = wid * 32 + j * 8 + (lane >> 3);
      int sc  = (lane & 7) ^ (row & 7);
      async_copy16(Bw + (size_t)(n0 + row) * 1024 + k0 + sc * 8,
                   b_lds + (wid * 32 + j * 8) * 64);
      async_copy16(Ab + (size_t)(m0 + row) * 1024 + k0 + sc * 8,
                   a_lds + (wid * 32 + j * 8) * 64);
    }
    asm volatile("s_waitcnt vmcnt(0)" ::: "memory");
    __syncthreads();

    #pragma unroll
    for (int s32 = 0; s32 < 2; ++s32) {
      bf16x8 af[4], bfr[4];
      #pragma unroll
      for (int mi = 0; mi < 4; ++mi) {
        int row = wm * 64 + mi * 16 + (lane & 15);
        int ch  = (s32 * 4 + (lane >> 4)) ^ (row & 7);
        af[mi] = *(const bf16x8*)(a_lds + row * 64 + ch * 8);
      }
      #pragma unroll
      for (int ni = 0; ni < 4; ++ni) {
        int row = wn * 64 + ni * 16 + (lane & 15);
        int ch  = (s32 * 4 + (lane >> 4)) ^ (row & 7);
        bfr[ni] = *(const bf16x8*)(b_lds + row * 64 + ch * 8);
      }
      #pragma unroll
      for (int mi = 0; mi < 4; ++mi)
        #pragma unroll
        for (int ni = 0; ni < 4; ++ni)
          acc[mi][ni] = __builtin_amdgcn_mfma_f32_16x16x32_bf16(af[mi], bfr[ni], acc[mi][ni], 0, 0, 0);
    }
  }

  // A rows are b*2048+s ; out is [s][b][d]
  #pragma unroll
  for (int ni = 0; ni < 4; ++ni) {
    int n = n0 + wn * 64 + ni * 16 + (lane & 15);
    float bv = bias[n];
    #pragma unroll
    for (int mi = 0; mi < 4; ++mi) {
      int sbase = m0 + wm * 64 + mi * 16 + ((lane >> 4) << 2);
      #pragma unroll
      for (int r = 0; r < 4; ++r) {
        int m = sbase + r;
        int bb = m >> 11, s = m & 2047;
        outp[((size_t)(s * NB + bb)) * 1024 + n] = acc[mi][ni][r] + bv;
      }
    }
  }
}

// ---------------- flash attention, 8-wave 32x32 swapped-QK ----------------
// Qb: [bh][s][dk] bf16 (pre-scaled). Kb: row-swizzled. Vt: [bh][dk][s'] swizzled.
// STATIC-STABILITY SOFTMAX: P = exp2(s) directly; l = exact fp32 row sum.
__global__ __launch_bounds__(512, 4) void attn_kernel(const u16* __restrict__ Qb,
                                                      const u16* __restrict__ Kb,
                                                      const u16* __restrict__ Vt,
                                                      u16* __restrict__ Oatt) {
  __shared__ u16 kbuf[2][64 * 64];
  __shared__ u16 vbuf[2][64 * 64];
  __shared__ float alds[8][32];
  const int tid = threadIdx.x;
  const int w = tid >> 6, lane = tid & 63;
  const int hi = lane >> 5, l31 = lane & 31;
  const int lin = blockIdx.x;
  const int bh = (lin & 7) + 8 * (lin >> 6);   // XCD = bh & 7
  const int qt = (lin >> 3) & 7;
  const int h = bh & 15, b = bh >> 4;
  const int q0 = qt * 256 + w * 32;
  const int key = l31 & 15;

  bf16x8 qf[4];
  {
    const u16* qp = Qb + ((size_t)bh * S_LEN + q0 + l31) * HD + hi * 8;
    #pragma unroll
    for (int s = 0; s < 4; ++s) qf[s] = *(const bf16x8*)(qp + s * 16);
  }

  f32x16 acc0 = {}, acc1 = {};
  float l_run = 0.0f;

  const int rl = w * 8 + (lane >> 3);
  const u16* ksrc = Kb + ((size_t)bh * S_LEN + rl) * HD + (lane & 7) * 8;
  const u16* vsrc = Vt + ((size_t)bh * HD + rl) * S_LEN + (lane & 7) * 8;

  async_copy16(ksrc, &kbuf[0][w * 512]);
  async_copy16(vsrc, &vbuf[0][w * 512]);
  asm volatile("s_waitcnt vmcnt(0)" ::: "memory");
  __syncthreads();

  for (int kb = 0; kb < 32; ++kb) {
    const int cur = kb & 1;
    if (kb + 1 < 32) {
      async_copy16(ksrc + (size_t)(kb + 1) * 64 * HD, &kbuf[cur ^ 1][w * 512]);
      async_copy16(vsrc + (kb + 1) * 64, &vbuf[cur ^ 1][w * 512]);
    }
    const u16* KL = kbuf[cur];
    const u16* VL = vbuf[cur];

    // ---- QK^T (swapped): D[k][q], col q = lane&31; conflict-free b64 pairs
    f32x16 pk0 = {}, pk1 = {};
    __builtin_amdgcn_s_setprio(1);
    #pragma unroll
    for (int s = 0; s < 4; ++s) {
      const int c0 = 4 * s + 2 * hi;
      const int p0 = (c0 ^ key) * 4;
      const int p1 = ((c0 + 1) ^ key) * 4;
      uint2 a0 = *(const uint2*)(KL + l31 * 64 + p0);
      uint2 a1 = *(const uint2*)(KL + l31 * 64 + p1);
      uint2 b0 = *(const uint2*)(KL + (32 + l31) * 64 + p0);
      uint2 b1 = *(const uint2*)(KL + (32 + l31) * 64 + p1);
      u32x4 kw0 = {a0.x, a0.y, a1.x, a1.y};
      u32x4 kw1 = {b0.x, b0.y, b1.x, b1.y};
      pk0 = __builtin_amdgcn_mfma_f32_32x32x16_bf16(__builtin_bit_cast(bf16x8, kw0), qf[s], pk0, 0, 0, 0);
      pk1 = __builtin_amdgcn_mfma_f32_32x32x16_bf16(__builtin_bit_cast(bf16x8, kw1), qf[s], pk1, 0, 0, 0);
    }
    __builtin_amdgcn_s_setprio(0);

    // ---- softmax numerator: P = exp2(s) directly (statically stable)
    #pragma unroll
    for (int r = 0; r < 16; ++r) {
      pk0[r] = fast_exp2(pk0[r]);
      pk1[r] = fast_exp2(pk1[r]);
    }

    // ---- row-sum (q-domain scalar l), pairwise tree
    {
      float t16[16];
      #pragma unroll
      for (int r = 0; r < 16; ++r) t16[r] = pk0[r] + pk1[r];
      float t8[8];
      #pragma unroll
      for (int r = 0; r < 8; ++r) t8[r] = t16[r] + t16[r + 8];
      float t4[4];
      #pragma unroll
      for (int r = 0; r < 4; ++r) t4[r] = t8[r] + t8[r + 4];
      float rs = (t4[0] + t4[1]) + (t4[2] + t4[3]);
#if __has_builtin(__builtin_amdgcn_permlane32_swap)
      u32 ru = __builtin_bit_cast(u32, rs);
      auto sw = __builtin_amdgcn_permlane32_swap(ru, ru, false, false);
      rs += __builtin_bit_cast(float, hi ? sw[0] : sw[1]);
#else
      rs += __shfl_xor(rs, 32);
#endif
      l_run += rs;
    }

    // ---- P -> bf16 (cvt_pk) then per-half A-frag build + PV MFMA
    u32 c0v[8], c1v[8];
    #pragma unroll
    for (int i = 0; i < 8; ++i) {
      float a0 = pk0[2 * i], b0 = pk0[2 * i + 1];
      float a1 = pk1[2 * i], b1 = pk1[2 * i + 1];
      asm("v_cvt_pk_bf16_f32 %0, %1, %2" : "=v"(c0v[i]) : "v"(a0), "v"(b0));
      asm("v_cvt_pk_bf16_f32 %0, %1, %2" : "=v"(c1v[i]) : "v"(a1), "v"(b1));
    }

    __builtin_amdgcn_s_setprio(1);
    #pragma unroll
    for (int g = 0; g < 2; ++g) {
      u32 pa0[4], pa1[4];
#if __has_builtin(__builtin_amdgcn_permlane32_swap)
      {
        auto s0 = __builtin_amdgcn_permlane32_swap(c0v[4*g+0], c0v[4*g+2], false, false);
        auto s1 = __builtin_amdgcn_permlane32_swap(c0v[4*g+1], c0v[4*g+3], false, false);
        pa0[0] = s0[0]; pa0[2] = s0[1]; pa0[1] = s1[0]; pa0[3] = s1[1];
        auto t0 = __builtin_amdgcn_permlane32_swap(c1v[4*g+0], c1v[4*g+2], false, false);
        auto t1 = __builtin_amdgcn_permlane32_swap(c1v[4*g+1], c1v[4*g+3], false, false);
        pa1[0] = t0[0]; pa1[2] = t0[1]; pa1[1] = t1[0]; pa1[3] = t1[1];
      }
#else
      {
        u32 x0 = c0v[4*g+0], x1 = c0v[4*g+1], y0 = c0v[4*g+2], y1 = c0v[4*g+3];
        u32 X0 = __shfl_xor((int)x0, 32), X1 = __shfl_xor((int)x1, 32);
        u32 Y0 = __shfl_xor((int)y0, 32), Y1 = __shfl_xor((int)y1, 32);
        pa0[0] = hi ? Y0 : x0; pa0[1] = hi ? Y1 : x1;
        pa0[2] = hi ? y0 : X0; pa0[3] = hi ? y1 : X1;
        x0 = c1v[4*g+0]; x1 = c1v[4*g+1]; y0 = c1v[4*g+2]; y1 = c1v[4*g+3];
        X0 = __shfl_xor((int)x0, 32); X1 = __shfl_xor((int)x1, 32);
        Y0 = __shfl_xor((int)y0, 32); Y1 = __shfl_xor((int)y1, 32);
        pa1[0] = hi ? Y0 : x0; pa1[1] = hi ? Y1 : x1;
        pa1[2] = hi ? y0 : X0; pa1[3] = hi ? y1 : X1;
      }
#endif
      #pragma unroll
      for (int t = 0; t < 2; ++t) {
        const int ks = t == 0 ? g : 2 + g;
        u32x4 pw = t == 0 ? (u32x4){pa0[0], pa0[1], pa0[2], pa0[3]}
                          : (u32x4){pa1[0], pa1[1], pa1[2], pa1[3]};
        bf16x8 paf = __builtin_bit_cast(bf16x8, pw);
        const int c0c = 4 * ks + 2 * hi;
        const int p0 = (c0c ^ key) * 4;
        const int p1 = ((c0c + 1) ^ key) * 4;
        uint2 va0 = *(const uint2*)(VL + l31 * 64 + p0);
        uint2 va1 = *(const uint2*)(VL + l31 * 64 + p1);
        uint2 vb0 = *(const uint2*)(VL + (32 + l31) * 64 + p0);
        uint2 vb1 = *(const uint2*)(VL + (32 + l31) * 64 + p1);
        u32x4 vw0 = {va0.x, va0.y, va1.x, va1.y};
        u32x4 vw1 = {vb0.x, vb0.y, vb1.x, vb1.y};
        acc0 = __builtin_amdgcn_mfma_f32_32x32x16_bf16(paf, __builtin_bit_cast(bf16x8, vw0), acc0, 0, 0, 0);
        acc1 = __builtin_amdgcn_mfma_f32_32x32x16_bf16(paf, __builtin_bit_cast(bf16x8, vw1), acc1, 0, 0, 0);
      }
    }
    __builtin_amdgcn_s_setprio(0);

    asm volatile("s_waitcnt vmcnt(0)" ::: "memory");
    __syncthreads();
  }

  // ---- epilogue: broadcast l to C-row domain, O = acc / l
  if (lane < 32) alds[w][l31] = l_run;
  #pragma unroll
  for (int r = 0; r < 16; ++r) {
    const int crow = (r & 3) + 8 * (r >> 2) + 4 * hi;
    const int q = q0 + crow;
    u16* op = Oatt + ((size_t)b * S_LEN + q) * DMOD + h * HD;
    const float inv = 1.0f / alds[w][crow];
    op[l31]      = f32_to_bf16(acc0[r] * inv);
    op[32 + l31] = f32_to_bf16(acc1[r] * inv);
  }
}

// ---------------- launch ----------------
extern "C" void kernel_launch(void* const* d_in, const int* in_sizes, int n_in,
                              void* d_out, int out_size, void* d_ws, size_t ws_size,
                              hipStream_t stream) {
  const float* Xq = (const float*)d_in[0];
  const float* Xk = (const float*)d_in[1];
  const float* Xv = (const float*)d_in[2];
  const float* Wq = (const float*)d_in[3];
  const float* bq = (const float*)d_in[4];
  const float* Wk = (const float*)d_in[5];
  const float* bk = (const float*)d_in[6];
  const float* Wv = (const float*)d_in[7];
  const float* bv = (const float*)d_in[8];
  const float* Wo = (const float*)d_in[9];
  const float* bo = (const float*)d_in[10];

  u16* Wqb = (u16*)d_ws;
  u16* Wkb = Wqb + (1 << 20);
  u16* Wvb = Wkb + (1 << 20);
  u16* Wob = Wvb + (1 << 20);
  u16* Qb  = Wob + (1 << 20);
  const size_t QKV = (size_t)64 * S_LEN * HD;  // 8388608 elems
  u16* Kb  = Qb + QKV;
  u16* Vt  = Kb + QKV;
  u16* Oat = Vt + QKV;

  convert4_kernel<<<dim3(1024, 4), 256, 0, stream>>>(Wq, Wk, Wv, Wo, Wqb, Wkb, Wvb, Wob);

  // Q pre-scaled by (1/sqrt(64)) * log2(e) so softmax runs in exp2 domain
  gemm_proj<<<dim3(64, 8, 3), 256, 0, stream>>>(Xq, Xk, Xv, Wqb, Wkb, Wvb,
                                                bq, bk, bv, Qb, Kb, Vt,
                                                0.125f * 1.4426950408889634f);

  attn_kernel<<<dim3(512), 512, 0, stream>>>(Qb, Kb, Vt, Oat);

  gemm_out<<<dim3(64, 8), 256, 0, stream>>>(Oat, Wob, bo, (float*)d_out);
}